// Round 25
// baseline (3470.242 us; speedup 1.0000x reference)
//
#include <hip/hip_runtime.h>
#include <math.h>

#define S 512
#define B 64
#define I 1024
#define HD 1024
#define G4 (4*HD)
#define NB 256
#define POIS 0xFFFFFFFFFFFFFFFFull

typedef _Float16 half8 __attribute__((ext_vector_type(8)));
typedef float floatx4 __attribute__((ext_vector_type(4)));
typedef float f32x4 __attribute__((ext_vector_type(4)));
typedef unsigned uint4v __attribute__((ext_vector_type(4)));

// ---------- prep kernels ----------

__global__ void cast_f32_to_f16(const float* __restrict__ src,
                                _Float16* __restrict__ dst, long n8) {
    long i = (long)blockIdx.x * blockDim.x + threadIdx.x;
    if (i >= n8) return;
    const f32x4* s = (const f32x4*)src + i * 2;
    f32x4 a = s[0], b = s[1];
    half8 h;
    h[0] = (_Float16)a[0]; h[1] = (_Float16)a[1];
    h[2] = (_Float16)a[2]; h[3] = (_Float16)a[3];
    h[4] = (_Float16)b[0]; h[5] = (_Float16)b[1];
    h[6] = (_Float16)b[2]; h[7] = (_Float16)b[3];
    *((half8*)dst + i) = h;
}

__global__ void init_state(const float* __restrict__ h0,
                           const float* __restrict__ bi, const float* __restrict__ bh,
                           _Float16* __restrict__ ring0, float* __restrict__ bsum) {
    int i = blockIdx.x * blockDim.x + threadIdx.x;
    if (i < B * HD) ring0[i] = (_Float16)h0[i];   // slot 0 = h0 (overwrites poison)
    if (i < G4) bsum[i] = bi[i] + bh[i];
}

// ---------- persistent recurrent kernel ----------
// R25 = R24 (trunk, 2269us) with ONE structural change: ACCX loads x
// B-fragments DIRECTLY from the f16 xb (R14-R17 proven pattern; all 4 waves
// share bg so the frag addresses are wave-identical; 4x L2-read redundancy
// ~32MB/step, overlappable). Deletes the STAGE_X LDS round-trip and cuts
// syncs 4 -> 2/step: acch -> gates -> publish -> ACCX_DIRECT (hides publish
// flight) -> sync -> poll -> sync. hfrag is h-only (no time-mux).
// Geometry/handoff identical to R18/R22/R24: 256 blocks x 256 threads,
// 1 block/CU; block m: rg=m>>2 hidden [16rg,+16), bg=m&3 batches [16bg,+16);
// Wi pinned in 128 AGPRs; 512-deep poisoned ring (0xFFFF f16 = NaN,
// unforgeable); publish = agent relaxed atomic store per quad; consume =
// wave-coherent batched sc1 poll w/backoff. No grid barrier, plain launch.

__global__ __launch_bounds__(256, 1) void lstm_persistent(
    const _Float16* __restrict__ xb,     // (S,B,I) f16
    const _Float16* __restrict__ Wib,
    const _Float16* __restrict__ Whb,
    const float*    __restrict__ bsum,
    const float*    __restrict__ c0,
    _Float16*       __restrict__ ring,   // S slots x (B*HD) f16
    float*          __restrict__ out)
{
    __shared__ alignas(16) _Float16 fragWh[65536];  // 128 KB
    __shared__ alignas(16) _Float16 hfrag[16384];   // 32 KB (h only)

    const int m = blockIdx.x;
    const int rg = m >> 2;
    const int bg = m & 3;
    const int tid = threadIdx.x;
    const int l = tid & 63, w = tid >> 6;

    // ---- stage Wh fragments into LDS (64 rows, frag order) ----
    for (int idx = tid; idx < 64 * 128; idx += 256) {
        int r_loc = idx >> 7;
        int ch = idx & 127;
        int wv = r_loc >> 4, rr = r_loc & 15;
        int kstep = ch >> 2, sub = ch & 3;
        int lane = sub * 16 + rr;
        int grow = (rr & 3) * HD + (rg * 16 + wv * 4 + (rr >> 2));
        int dst = wv * 16384 + kstep * 512 + lane * 8;
        *(half8*)&fragWh[dst] = *(const half8*)&Whb[(size_t)grow * HD + ch * 8];
    }

    // ---- Wi fragments -> registers, then PIN IN AGPRs (resident) ----
    uint4v wif[32];
    {
        int rr = l & 15;
        int grow = (rr & 3) * HD + (rg * 16 + w * 4 + (rr >> 2));
        const _Float16* wrow = Wib + (size_t)grow * I + (l >> 4) * 8;
        #pragma unroll
        for (int kk = 0; kk < 32; ++kk)
            wif[kk] = *(const uint4v*)(wrow + kk * 32);
        #pragma unroll
        for (int kk = 0; kk < 32; ++kk)
            asm volatile("" : "+a"(wif[kk]));   // force into AGPRs (opaque)
    }

    const int bq = bg * 16 + (l & 15);
    const int jq = rg * 16 + w * 4;
    const int j  = jq + (l >> 4);
    const float b0 = bsum[j];
    const float b1 = bsum[HD + j];
    const float b2 = bsum[2 * HD + j];
    const float b3 = bsum[3 * HD + j];
    const size_t cix = (size_t)bq * HD + j;
    float c = c0[cix];

    // h-slice chunk offsets: chunk cc -> kstep kk=cc*4+w, 16B at
    // h[16bg+(l&15)][(l>>4)*8 + kk*32]
    const size_t hoff[8] = {
        ((size_t)(bg * 16 + (l & 15)) * HD + (l >> 4) * 8 + (0 * 4 + w) * 32) * 2,
        ((size_t)(bg * 16 + (l & 15)) * HD + (l >> 4) * 8 + (1 * 4 + w) * 32) * 2,
        ((size_t)(bg * 16 + (l & 15)) * HD + (l >> 4) * 8 + (2 * 4 + w) * 32) * 2,
        ((size_t)(bg * 16 + (l & 15)) * HD + (l >> 4) * 8 + (3 * 4 + w) * 32) * 2,
        ((size_t)(bg * 16 + (l & 15)) * HD + (l >> 4) * 8 + (4 * 4 + w) * 32) * 2,
        ((size_t)(bg * 16 + (l & 15)) * HD + (l >> 4) * 8 + (5 * 4 + w) * 32) * 2,
        ((size_t)(bg * 16 + (l & 15)) * HD + (l >> 4) * 8 + (6 * 4 + w) * 32) * 2,
        ((size_t)(bg * 16 + (l & 15)) * HD + (l >> 4) * 8 + (7 * 4 + w) * 32) * 2};

    // accx: direct global loads of x B-frags (f16) x AGPR-resident Wi frags
    #define ACCX_DIRECT(dstacc, trow)                                           \
    {                                                                           \
        const _Float16* xrow_ = xb + ((size_t)(trow) * B + bq) * I + (l >> 4) * 8;\
        uint4v xld[32];                                                         \
        _Pragma("unroll")                                                       \
        for (int kk = 0; kk < 32; ++kk)                                         \
            xld[kk] = *(const uint4v*)(xrow_ + kk * 32);                        \
        floatx4 a_ = {0.f, 0.f, 0.f, 0.f};                                      \
        _Pragma("unroll")                                                       \
        for (int kk = 0; kk < 32; ++kk)                                         \
            a_ = __builtin_amdgcn_mfma_f32_16x16x32_f16(                        \
                __builtin_bit_cast(half8, wif[kk]),                             \
                __builtin_bit_cast(half8, xld[kk]), a_, 0, 0, 0);               \
        dstacc = a_;                                                            \
    }

    // wave-coherent batched poll + stage; gentle backoff after first miss
    #define LOAD_HFRAG(st)                                                      \
    {                                                                           \
        const char* sb = (const char*)(ring + (size_t)(st) * B * HD);           \
        uint4v o0,o1,o2,o3,o4,o5,o6,o7;                                         \
        int rounds = 0;                                                         \
        for (;;) {                                                              \
            asm volatile(                                                       \
                "global_load_dwordx4 %0, %8, off sc0 sc1\n\t"                   \
                "global_load_dwordx4 %1, %9, off sc0 sc1\n\t"                   \
                "global_load_dwordx4 %2, %10, off sc0 sc1\n\t"                  \
                "global_load_dwordx4 %3, %11, off sc0 sc1\n\t"                  \
                "global_load_dwordx4 %4, %12, off sc0 sc1\n\t"                  \
                "global_load_dwordx4 %5, %13, off sc0 sc1\n\t"                  \
                "global_load_dwordx4 %6, %14, off sc0 sc1\n\t"                  \
                "global_load_dwordx4 %7, %15, off sc0 sc1\n\t"                  \
                "s_waitcnt vmcnt(0)"                                            \
                : "=&v"(o0),"=&v"(o1),"=&v"(o2),"=&v"(o3),                      \
                  "=&v"(o4),"=&v"(o5),"=&v"(o6),"=&v"(o7)                       \
                : "v"(sb + hoff[0]),"v"(sb + hoff[1]),                          \
                  "v"(sb + hoff[2]),"v"(sb + hoff[3]),                          \
                  "v"(sb + hoff[4]),"v"(sb + hoff[5]),                          \
                  "v"(sb + hoff[6]),"v"(sb + hoff[7])                           \
                : "memory");                                                    \
            bool bad = false;                                                   \
            uint4v oo[8] = {o0,o1,o2,o3,o4,o5,o6,o7};                           \
            _Pragma("unroll")                                                   \
            for (int cc = 0; cc < 8; ++cc) {                                    \
                bad = bad || (oo[cc][0] == 0xFFFFFFFFu && oo[cc][1] == 0xFFFFFFFFu) \
                          || (oo[cc][2] == 0xFFFFFFFFu && oo[cc][3] == 0xFFFFFFFFu);\
            }                                                                   \
            if (!__any(bad)) break;                                             \
            if (rounds++ > 0) __builtin_amdgcn_s_sleep(2);                      \
        }                                                                       \
        *(uint4v*)&hfrag[(0 * 4 + w) * 512 + l * 8] = o0;                       \
        *(uint4v*)&hfrag[(1 * 4 + w) * 512 + l * 8] = o1;                       \
        *(uint4v*)&hfrag[(2 * 4 + w) * 512 + l * 8] = o2;                       \
        *(uint4v*)&hfrag[(3 * 4 + w) * 512 + l * 8] = o3;                       \
        *(uint4v*)&hfrag[(4 * 4 + w) * 512 + l * 8] = o4;                       \
        *(uint4v*)&hfrag[(5 * 4 + w) * 512 + l * 8] = o5;                       \
        *(uint4v*)&hfrag[(6 * 4 + w) * 512 + l * 8] = o6;                       \
        *(uint4v*)&hfrag[(7 * 4 + w) * 512 + l * 8] = o7;                       \
    }

    // ---- prologue: accx(0) direct; h0 -> hfrag ----
    floatx4 accx;
    ACCX_DIRECT(accx, 0)
    LOAD_HFRAG(0)
    __syncthreads();   // fragWh staged + hfrag(h0) ready

    for (int t = 0; t < S; ++t) {
        // ---- h-chain from LDS frags ----
        floatx4 acch = {0.f, 0.f, 0.f, 0.f};
        #pragma unroll
        for (int kk = 0; kk < 32; ++kk) {
            half8 ah  = *(const half8*)&fragWh[w * 16384 + kk * 512 + l * 8];
            half8 bhv = *(const half8*)&hfrag[kk * 512 + l * 8];
            acch = __builtin_amdgcn_mfma_f32_16x16x32_f16(ah, bhv, acch, 0, 0, 0);
        }

        // ---- gates ----
        float pi = accx[0] + acch[0] + b0;
        float pf = accx[1] + acch[1] + b1;
        float po = accx[2] + acch[2] + b2;
        float pg = accx[3] + acch[3] + b3;

        float ig = 1.f / (1.f + __expf(-pi));
        float fg = 1.f / (1.f + __expf(-pf));
        float og = 1.f / (1.f + __expf(-po));
        float gg = 1.f - 2.f / (__expf(2.f * pg) + 1.f);

        c = c * fg + ig * gg;
        float th = 1.f - 2.f / (__expf(2.f * c) + 1.f);
        float ht = og * th;

        // ---- pack quad (shuffles pre-divergence) ----
        unsigned hb16 = (unsigned)__builtin_bit_cast(unsigned short, (_Float16)ht);
        unsigned p16 = (unsigned)__shfl_xor((int)hb16, 16);
        unsigned pw0 = hb16 | (p16 << 16);
        unsigned long long p32 = (unsigned)__shfl_xor((int)pw0, 32);
        unsigned long long w64 = (unsigned long long)pw0 | (p32 << 32);
        float v1 = __shfl_xor(ht, 16);
        float v2 = __shfl_xor(ht, 32);
        float v3 = __shfl_xor(ht, 48);

        if (t == S - 1) {
            if ((l >> 4) == 0) {
                f32x4 o = {ht, v1, v2, v3};
                *(f32x4*)&out[((size_t)t * B + bq) * HD + jq] = o;
            }
            out[(size_t)S * B * HD + cix] = ht;                   // h_f
            out[(size_t)S * B * HD + (size_t)B * HD + cix] = c;   // c_f
            break;
        }

        // ---- publish h_{t+1}: agent relaxed atomic store per quad ----
        if ((l >> 4) == 0) {
            unsigned long long* wq =
                (unsigned long long*)(ring + (size_t)(t + 1) * B * HD)
                + ((size_t)bq * HD + jq) / 4;
            __hip_atomic_store(wq, w64, __ATOMIC_RELAXED,
                               __HIP_MEMORY_SCOPE_AGENT);
            f32x4 o = {ht, v1, v2, v3};
            *(f32x4*)&out[((size_t)t * B + bq) * HD + jq] = o;
        }

        // ---- accx(t+1): direct x loads + AGPR Wi (hides publish flight) ----
        floatx4 accx_n;
        ACCX_DIRECT(accx_n, t + 1)

        __syncthreads();   // all waves done reading hfrag(h_t)

        // ---- poll h_{t+1} (batched wave-coherent, backoff on misses) ----
        LOAD_HFRAG(t + 1)
        accx = accx_n;
        __syncthreads();   // hfrag(h_{t+1}) ready
    }
}

// ---------- launch ----------

extern "C" void kernel_launch(void* const* d_in, const int* in_sizes, int n_in,
                              void* d_out, int out_size, void* d_ws, size_t ws_size,
                              hipStream_t stream) {
    const float* x  = (const float*)d_in[0];
    const float* h0 = (const float*)d_in[1];
    const float* c0 = (const float*)d_in[2];
    const float* Wi = (const float*)d_in[3];
    const float* bi = (const float*)d_in[4];
    const float* Wh = (const float*)d_in[5];
    const float* bh = (const float*)d_in[6];
    float* out = (float*)d_out;

    char* p = (char*)d_ws;
    _Float16* Wib = (_Float16*)p; p += (size_t)G4 * I * 2;
    _Float16* Whb = (_Float16*)p; p += (size_t)G4 * HD * 2;
    float* bsum   = (float*)p;    p += (size_t)G4 * 4;
    _Float16* ring = (_Float16*)p; p += (size_t)S * B * HD * 2;   // 64 MB
    _Float16* xb  = (_Float16*)p; p += (size_t)S * B * I * 2;     // 64 MB

    // Poison the whole ring (f16 0xFFFF = NaN; h is always finite), then
    // overwrite slot 0 with h0.
    hipMemsetAsync(ring, 0xFF, (size_t)S * B * HD * 2, stream);

    long nw8 = (long)G4 * I / 8;
    cast_f32_to_f16<<<(int)((nw8 + 255) / 256), 256, 0, stream>>>(Wi, Wib, nw8);
    cast_f32_to_f16<<<(int)((nw8 + 255) / 256), 256, 0, stream>>>(Wh, Whb, nw8);
    long nx8 = (long)S * B * I / 8;
    cast_f32_to_f16<<<(int)((nx8 + 255) / 256), 256, 0, stream>>>(x, xb, nx8);
    init_state<<<(B * HD + 255) / 256, 256, 0, stream>>>(h0, bi, bh, ring, bsum);

    // Plain launch: 256 blocks (grid <= CU count -> all co-resident);
    // handoff is data-driven (no grid barrier, no coop launch).
    lstm_persistent<<<dim3(NB), 256, 0, stream>>>(
        xb, Wib, Whb, bsum, c0, ring, out);
}

// Round 26
// 2199.057 us; speedup vs baseline: 1.5781x; 1.5781x over previous
//
#include <hip/hip_runtime.h>
#include <math.h>

#define S 512
#define B 64
#define I 1024
#define HD 1024
#define G4 (4*HD)
#define NB 256
#define POIS 0xFFFFFFFFFFFFFFFFull

typedef _Float16 half8 __attribute__((ext_vector_type(8)));
typedef float floatx4 __attribute__((ext_vector_type(4)));
typedef float f32x4 __attribute__((ext_vector_type(4)));
typedef unsigned uint4v __attribute__((ext_vector_type(4)));

// ---------- prep kernels ----------

__global__ void cast_f32_to_f16(const float* __restrict__ src,
                                _Float16* __restrict__ dst, long n8) {
    long i = (long)blockIdx.x * blockDim.x + threadIdx.x;
    if (i >= n8) return;
    const f32x4* s = (const f32x4*)src + i * 2;
    f32x4 a = s[0], b = s[1];
    half8 h;
    h[0] = (_Float16)a[0]; h[1] = (_Float16)a[1];
    h[2] = (_Float16)a[2]; h[3] = (_Float16)a[3];
    h[4] = (_Float16)b[0]; h[5] = (_Float16)b[1];
    h[6] = (_Float16)b[2]; h[7] = (_Float16)b[3];
    *((half8*)dst + i) = h;
}

__global__ void init_state(const float* __restrict__ h0,
                           const float* __restrict__ bi, const float* __restrict__ bh,
                           _Float16* __restrict__ ring0, float* __restrict__ bsum) {
    int i = blockIdx.x * blockDim.x + threadIdx.x;
    if (i < B * HD) ring0[i] = (_Float16)h0[i];   // slot 0 = h0 (overwrites poison)
    if (i < G4) bsum[i] = bi[i] + bh[i];
}

// ---------- persistent recurrent kernel ----------
// R26 = R24 (trunk, 2269us) with EXACTLY ONE change: T14 async-STAGE split
// (guide G15, attn-proven). STAGE_X's 8 global x loads are issued at the
// TOP of the loop (STAGE_LOAD -> registers), hiding their ~500cyc L2
// latency under the acch MFMA chain + gates + publish; only the cheap LDS
// writes (STAGE_WRITE) remain in the post-publish serial window. (R25's
// direct-x-loads reverted: 4x L2 redundancy cost 1.2us/step.)
// Geometry/handoff identical to R24: 256 blocks x 256 threads, 1 block/CU
// (160KB LDS); block m: rg=m>>2 hidden [16rg,+16), bg=m&3 batches
// [16bg,+16); time-muxed hfrag (h_t | x(t+1)); Wi pinned in 128 AGPRs; x
// pre-cast to f16; 512-deep poisoned ring (0xFFFF f16 = NaN, unforgeable);
// publish = agent relaxed atomic store per quad; consume = wave-coherent
// batched sc1 poll w/backoff. No grid barrier, plain launch.

__global__ __launch_bounds__(256, 1) void lstm_persistent(
    const _Float16* __restrict__ xb,     // (S,B,I) f16
    const _Float16* __restrict__ Wib,
    const _Float16* __restrict__ Whb,
    const float*    __restrict__ bsum,
    const float*    __restrict__ c0,
    _Float16*       __restrict__ ring,   // S slots x (B*HD) f16
    float*          __restrict__ out)
{
    __shared__ alignas(16) _Float16 fragWh[65536];  // 128 KB
    __shared__ alignas(16) _Float16 hfrag[16384];   // 32 KB (h_t | x(t+1) mux)

    const int m = blockIdx.x;
    const int rg = m >> 2;
    const int bg = m & 3;
    const int tid = threadIdx.x;
    const int l = tid & 63, w = tid >> 6;

    // ---- stage Wh fragments into LDS (64 rows, frag order) ----
    for (int idx = tid; idx < 64 * 128; idx += 256) {
        int r_loc = idx >> 7;
        int ch = idx & 127;
        int wv = r_loc >> 4, rr = r_loc & 15;
        int kstep = ch >> 2, sub = ch & 3;
        int lane = sub * 16 + rr;
        int grow = (rr & 3) * HD + (rg * 16 + wv * 4 + (rr >> 2));
        int dst = wv * 16384 + kstep * 512 + lane * 8;
        *(half8*)&fragWh[dst] = *(const half8*)&Whb[(size_t)grow * HD + ch * 8];
    }

    // ---- Wi fragments -> registers, then PIN IN AGPRs (resident) ----
    uint4v wif[32];
    {
        int rr = l & 15;
        int grow = (rr & 3) * HD + (rg * 16 + w * 4 + (rr >> 2));
        const _Float16* wrow = Wib + (size_t)grow * I + (l >> 4) * 8;
        #pragma unroll
        for (int kk = 0; kk < 32; ++kk)
            wif[kk] = *(const uint4v*)(wrow + kk * 32);
        #pragma unroll
        for (int kk = 0; kk < 32; ++kk)
            asm volatile("" : "+a"(wif[kk]));   // force into AGPRs (opaque)
    }

    const int bq = bg * 16 + (l & 15);
    const int jq = rg * 16 + w * 4;
    const int j  = jq + (l >> 4);
    const float b0 = bsum[j];
    const float b1 = bsum[HD + j];
    const float b2 = bsum[2 * HD + j];
    const float b3 = bsum[3 * HD + j];
    const size_t cix = (size_t)bq * HD + j;
    float c = c0[cix];

    // h-slice chunk offsets: chunk cc -> kstep kk=cc*4+w, 16B at
    // h[16bg+(l&15)][(l>>4)*8 + kk*32]
    const size_t hoff[8] = {
        ((size_t)(bg * 16 + (l & 15)) * HD + (l >> 4) * 8 + (0 * 4 + w) * 32) * 2,
        ((size_t)(bg * 16 + (l & 15)) * HD + (l >> 4) * 8 + (1 * 4 + w) * 32) * 2,
        ((size_t)(bg * 16 + (l & 15)) * HD + (l >> 4) * 8 + (2 * 4 + w) * 32) * 2,
        ((size_t)(bg * 16 + (l & 15)) * HD + (l >> 4) * 8 + (3 * 4 + w) * 32) * 2,
        ((size_t)(bg * 16 + (l & 15)) * HD + (l >> 4) * 8 + (4 * 4 + w) * 32) * 2,
        ((size_t)(bg * 16 + (l & 15)) * HD + (l >> 4) * 8 + (5 * 4 + w) * 32) * 2,
        ((size_t)(bg * 16 + (l & 15)) * HD + (l >> 4) * 8 + (6 * 4 + w) * 32) * 2,
        ((size_t)(bg * 16 + (l & 15)) * HD + (l >> 4) * 8 + (7 * 4 + w) * 32) * 2};

    // T14 split: issue 8 global x loads into registers (latency hides under
    // acch+gates+publish); LDS writes happen later in STAGE_WRITE.
    uint4v xpre[8];
    #define STAGE_LOAD(trow)                                                    \
    {                                                                           \
        const _Float16* xrow_ = xb + ((size_t)(trow) * B + bq) * I + (l >> 4) * 8;\
        _Pragma("unroll")                                                       \
        for (int cq = 0; cq < 8; ++cq)                                          \
            xpre[cq] = *(const uint4v*)(xrow_ + (w * 8 + cq) * 32);             \
    }
    #define STAGE_WRITE()                                                       \
    {                                                                           \
        _Pragma("unroll")                                                       \
        for (int cq = 0; cq < 8; ++cq)                                          \
            *(uint4v*)&hfrag[(w * 8 + cq) * 512 + l * 8] = xpre[cq];            \
    }

    // accx from hfrag x-frags + AGPR-resident Wi frags
    #define ACCX_FROM_LDS(dstacc)                                               \
    {                                                                           \
        floatx4 a_ = {0.f, 0.f, 0.f, 0.f};                                      \
        _Pragma("unroll")                                                       \
        for (int kk = 0; kk < 32; ++kk) {                                       \
            half8 bx = *(const half8*)&hfrag[kk * 512 + l * 8];                 \
            a_ = __builtin_amdgcn_mfma_f32_16x16x32_f16(                        \
                __builtin_bit_cast(half8, wif[kk]), bx, a_, 0, 0, 0);           \
        }                                                                       \
        dstacc = a_;                                                            \
    }

    // wave-coherent batched poll + stage; gentle backoff after first miss
    #define LOAD_HFRAG(st)                                                      \
    {                                                                           \
        const char* sb = (const char*)(ring + (size_t)(st) * B * HD);           \
        uint4v o0,o1,o2,o3,o4,o5,o6,o7;                                         \
        int rounds = 0;                                                         \
        for (;;) {                                                              \
            asm volatile(                                                       \
                "global_load_dwordx4 %0, %8, off sc0 sc1\n\t"                   \
                "global_load_dwordx4 %1, %9, off sc0 sc1\n\t"                   \
                "global_load_dwordx4 %2, %10, off sc0 sc1\n\t"                  \
                "global_load_dwordx4 %3, %11, off sc0 sc1\n\t"                  \
                "global_load_dwordx4 %4, %12, off sc0 sc1\n\t"                  \
                "global_load_dwordx4 %5, %13, off sc0 sc1\n\t"                  \
                "global_load_dwordx4 %6, %14, off sc0 sc1\n\t"                  \
                "global_load_dwordx4 %7, %15, off sc0 sc1\n\t"                  \
                "s_waitcnt vmcnt(0)"                                            \
                : "=&v"(o0),"=&v"(o1),"=&v"(o2),"=&v"(o3),                      \
                  "=&v"(o4),"=&v"(o5),"=&v"(o6),"=&v"(o7)                       \
                : "v"(sb + hoff[0]),"v"(sb + hoff[1]),                          \
                  "v"(sb + hoff[2]),"v"(sb + hoff[3]),                          \
                  "v"(sb + hoff[4]),"v"(sb + hoff[5]),                          \
                  "v"(sb + hoff[6]),"v"(sb + hoff[7])                           \
                : "memory");                                                    \
            bool bad = false;                                                   \
            uint4v oo[8] = {o0,o1,o2,o3,o4,o5,o6,o7};                           \
            _Pragma("unroll")                                                   \
            for (int cc = 0; cc < 8; ++cc) {                                    \
                bad = bad || (oo[cc][0] == 0xFFFFFFFFu && oo[cc][1] == 0xFFFFFFFFu) \
                          || (oo[cc][2] == 0xFFFFFFFFu && oo[cc][3] == 0xFFFFFFFFu);\
            }                                                                   \
            if (!__any(bad)) break;                                             \
            if (rounds++ > 0) __builtin_amdgcn_s_sleep(2);                      \
        }                                                                       \
        *(uint4v*)&hfrag[(0 * 4 + w) * 512 + l * 8] = o0;                       \
        *(uint4v*)&hfrag[(1 * 4 + w) * 512 + l * 8] = o1;                       \
        *(uint4v*)&hfrag[(2 * 4 + w) * 512 + l * 8] = o2;                       \
        *(uint4v*)&hfrag[(3 * 4 + w) * 512 + l * 8] = o3;                       \
        *(uint4v*)&hfrag[(4 * 4 + w) * 512 + l * 8] = o4;                       \
        *(uint4v*)&hfrag[(5 * 4 + w) * 512 + l * 8] = o5;                       \
        *(uint4v*)&hfrag[(6 * 4 + w) * 512 + l * 8] = o6;                       \
        *(uint4v*)&hfrag[(7 * 4 + w) * 512 + l * 8] = o7;                       \
    }

    // ---- prologue: x(0) -> hfrag -> accx(0); then h0 -> hfrag ----
    __syncthreads();   // fragWh staged
    STAGE_LOAD(0)
    STAGE_WRITE()
    __syncthreads();
    floatx4 accx;
    ACCX_FROM_LDS(accx)
    __syncthreads();   // accx reads done; hfrag free
    LOAD_HFRAG(0)
    __syncthreads();   // hfrag(h0) ready

    for (int t = 0; t < S; ++t) {
        // ---- T14: issue x(t+1) loads now; latency hides under acch ----
        {
            int tn = (t + 1 < S) ? (t + 1) : t;   // clamp: last-iter values unused
            STAGE_LOAD(tn)
        }

        // ---- h-chain from LDS frags ----
        floatx4 acch = {0.f, 0.f, 0.f, 0.f};
        #pragma unroll
        for (int kk = 0; kk < 32; ++kk) {
            half8 ah  = *(const half8*)&fragWh[w * 16384 + kk * 512 + l * 8];
            half8 bhv = *(const half8*)&hfrag[kk * 512 + l * 8];
            acch = __builtin_amdgcn_mfma_f32_16x16x32_f16(ah, bhv, acch, 0, 0, 0);
        }

        // ---- gates ----
        float pi = accx[0] + acch[0] + b0;
        float pf = accx[1] + acch[1] + b1;
        float po = accx[2] + acch[2] + b2;
        float pg = accx[3] + acch[3] + b3;

        float ig = 1.f / (1.f + __expf(-pi));
        float fg = 1.f / (1.f + __expf(-pf));
        float og = 1.f / (1.f + __expf(-po));
        float gg = 1.f - 2.f / (__expf(2.f * pg) + 1.f);

        c = c * fg + ig * gg;
        float th = 1.f - 2.f / (__expf(2.f * c) + 1.f);
        float ht = og * th;

        // ---- pack quad (shuffles pre-divergence) ----
        unsigned hb16 = (unsigned)__builtin_bit_cast(unsigned short, (_Float16)ht);
        unsigned p16 = (unsigned)__shfl_xor((int)hb16, 16);
        unsigned pw0 = hb16 | (p16 << 16);
        unsigned long long p32 = (unsigned)__shfl_xor((int)pw0, 32);
        unsigned long long w64 = (unsigned long long)pw0 | (p32 << 32);
        float v1 = __shfl_xor(ht, 16);
        float v2 = __shfl_xor(ht, 32);
        float v3 = __shfl_xor(ht, 48);

        if (t == S - 1) {
            if ((l >> 4) == 0) {
                f32x4 o = {ht, v1, v2, v3};
                *(f32x4*)&out[((size_t)t * B + bq) * HD + jq] = o;
            }
            out[(size_t)S * B * HD + cix] = ht;                   // h_f
            out[(size_t)S * B * HD + (size_t)B * HD + cix] = c;   // c_f
            break;
        }

        // ---- publish h_{t+1}: agent relaxed atomic store per quad ----
        if ((l >> 4) == 0) {
            unsigned long long* wq =
                (unsigned long long*)(ring + (size_t)(t + 1) * B * HD)
                + ((size_t)bq * HD + jq) / 4;
            __hip_atomic_store(wq, w64, __ATOMIC_RELAXED,
                               __HIP_MEMORY_SCOPE_AGENT);
            f32x4 o = {ht, v1, v2, v3};
            *(f32x4*)&out[((size_t)t * B + bq) * HD + jq] = o;
        }

        __syncthreads();   // hfrag(h_t) consumed by all waves

        // ---- write prefetched x(t+1) into hfrag (cheap LDS writes) ----
        STAGE_WRITE()
        __syncthreads();

        // ---- accx(t+1): AGPR Wi x hfrag x-frags (publish flight overlaps) ----
        floatx4 accx_n;
        ACCX_FROM_LDS(accx_n)
        __syncthreads();   // accx reads done; hfrag free

        // ---- poll h_{t+1} (batched wave-coherent, backoff on misses) ----
        LOAD_HFRAG(t + 1)
        accx = accx_n;
        __syncthreads();   // hfrag(h_{t+1}) ready
    }
}

// ---------- launch ----------

extern "C" void kernel_launch(void* const* d_in, const int* in_sizes, int n_in,
                              void* d_out, int out_size, void* d_ws, size_t ws_size,
                              hipStream_t stream) {
    const float* x  = (const float*)d_in[0];
    const float* h0 = (const float*)d_in[1];
    const float* c0 = (const float*)d_in[2];
    const float* Wi = (const float*)d_in[3];
    const float* bi = (const float*)d_in[4];
    const float* Wh = (const float*)d_in[5];
    const float* bh = (const float*)d_in[6];
    float* out = (float*)d_out;

    char* p = (char*)d_ws;
    _Float16* Wib = (_Float16*)p; p += (size_t)G4 * I * 2;
    _Float16* Whb = (_Float16*)p; p += (size_t)G4 * HD * 2;
    float* bsum   = (float*)p;    p += (size_t)G4 * 4;
    _Float16* ring = (_Float16*)p; p += (size_t)S * B * HD * 2;   // 64 MB
    _Float16* xb  = (_Float16*)p; p += (size_t)S * B * I * 2;     // 64 MB

    // Poison the whole ring (f16 0xFFFF = NaN; h is always finite), then
    // overwrite slot 0 with h0.
    hipMemsetAsync(ring, 0xFF, (size_t)S * B * HD * 2, stream);

    long nw8 = (long)G4 * I / 8;
    cast_f32_to_f16<<<(int)((nw8 + 255) / 256), 256, 0, stream>>>(Wi, Wib, nw8);
    cast_f32_to_f16<<<(int)((nw8 + 255) / 256), 256, 0, stream>>>(Wh, Whb, nw8);
    long nx8 = (long)S * B * I / 8;
    cast_f32_to_f16<<<(int)((nx8 + 255) / 256), 256, 0, stream>>>(x, xb, nx8);
    init_state<<<(B * HD + 255) / 256, 256, 0, stream>>>(h0, bi, bh, ring, bsum);

    // Plain launch: 256 blocks (grid <= CU count -> all co-resident);
    // handoff is data-driven (no grid barrier, no coop launch).
    lstm_persistent<<<dim3(NB), 256, 0, stream>>>(
        xb, Wib, Whb, bsum, c0, ring, out);
}